// Round 7
// baseline (102.563 us; speedup 1.0000x reference)
//
#include <hip/hip_runtime.h>
#include <math.h>

#define M_ROWS 8192   // B*S
#define KDIM   8192   // V
#define NDIM   512    // D
#define RCAP   512    // pair slots per row (mean nnz 82, sigma 9 -> 47-sigma)

typedef float    f32x4  __attribute__((ext_vector_type(4)));
typedef unsigned u32x4  __attribute__((ext_vector_type(4)));
typedef __bf16   bf16x8 __attribute__((ext_vector_type(8)));

// d_ws layout:  [0, 8M)  WT bf16 [8192][512]
//               [8M,24M) glist   u32  [8192][512]  (bf16 val | v)
//               [24M, +128K) count4 u32x4 [8192]   cumulative quarter counts
#define WS_GLIST  (8u  * 1024 * 1024)
#define WS_COUNT  (24u * 1024 * 1024)

// ---------------------------------------------------------------------------
// K1: W [512, 8192] f32 -> WT [8192, 512] bf16.
__global__ __launch_bounds__(256)
void transpose_w(const float* __restrict__ W, __bf16* __restrict__ WT) {
  __shared__ float tile[64][65];
  const int t  = threadIdx.x;
  const int v0 = (blockIdx.x & 127) << 6;
  const int d0 = (blockIdx.x >> 7) << 6;
  #pragma unroll
  for (int i = 0; i < 4; ++i) {
    int idx = i * 256 + t;
    int r = idx >> 4;
    int c = (idx & 15) << 2;
    f32x4 val = *(const f32x4*)(W + (size_t)(d0 + r) * KDIM + v0 + c);
    tile[r][c + 0] = val.x; tile[r][c + 1] = val.y;
    tile[r][c + 2] = val.z; tile[r][c + 3] = val.w;
  }
  __syncthreads();
  #pragma unroll
  for (int i = 0; i < 2; ++i) {
    int idx = i * 256 + t;
    int vr = idx >> 3;
    int d8 = (idx & 7) << 3;
    bf16x8 u;
    #pragma unroll
    for (int j = 0; j < 8; ++j) u[j] = (__bf16)tile[d8 + j][vr];
    *(bf16x8*)(WT + (size_t)(v0 + vr) * NDIM + d0 + d8) = u;
  }
}

// ---------------------------------------------------------------------------
// K2: pure scan+compact. One wave per row; 4-deep rotating prefetch so the
// 256 MB A-stream pipelines at HBM rate with no dependent gathers anywhere.
// Packs (bf16(val) | v) into 4 B; quarter-cumulative counts for K3 phasing.
__global__ __launch_bounds__(256)
void scan_compact(const float* __restrict__ A, unsigned* __restrict__ glist,
                  u32x4* __restrict__ count4) {
  const int lane = threadIdx.x & 63;
  const int m    = blockIdx.x * 4 + (threadIdx.x >> 6);
  const float* arow = A + (size_t)m * KDIM;
  unsigned* rl = glist + (size_t)m * RCAP;

  const unsigned long long ltmask = (1ull << lane) - 1ull;
  unsigned cur = 0;
  unsigned cq0 = 0, cq1 = 0, cq2 = 0;
  bool ovf = false;

  f32x4 bufs[4];
  #pragma unroll
  for (int p = 0; p < 4; ++p)
    bufs[p] = *(const f32x4*)(arow + p * 256 + lane * 4);

  #pragma unroll
  for (int pos = 0; pos < 32; ++pos) {          // 32 x 1 KB per wave
    f32x4 av = bufs[pos & 3];
    if (pos + 4 < 32)
      bufs[pos & 3] = *(const f32x4*)(arow + (pos + 4) * 256 + lane * 4);
    #pragma unroll
    for (int j = 0; j < 4; ++j) {
      unsigned long long msk = __ballot(av[j] != 0.0f);
      if (msk == 0) continue;
      unsigned cnt = (unsigned)__popcll(msk);
      if (cur + cnt <= RCAP) {
        if (av[j] != 0.0f) {
          unsigned pre = (unsigned)__popcll(msk & ltmask);
          unsigned fb  = (__float_as_uint(av[j]) + 0x8000u) & 0xFFFF0000u;
          rl[cur + pre] = fb | (unsigned)(pos * 256 + lane * 4 + j);
        }
        cur += cnt;
      } else {
        ovf = true;  // statistically unreachable at ~1% density
      }
    }
    if (pos == 7)  cq0 = cur;
    if (pos == 15) cq1 = cur;
    if (pos == 23) cq2 = cur;
  }
  if (lane == 0) {
    u32x4 c;
    c.x = ovf ? 0xFFFFFFFFu : cq0;
    c.y = cq1; c.z = cq2; c.w = cur;
    count4[m] = c;
  }
}

// ---------------------------------------------------------------------------
// K3: pure gather+FMA+tanh. One wave per row; pairs fetched one coalesced
// 32 B load per 8-group and shfl-broadcast; 8 gathers in flight; quarters
// processed in order so the live gather set is one 2 MB WT slice (L2-fits).
// Sentinel count -> exact direct re-scan of the row (overflow fallback).
__global__ __launch_bounds__(256)
void gather_tanh(const float* __restrict__ A, const __bf16* __restrict__ WT,
                 const unsigned* __restrict__ glist,
                 const u32x4* __restrict__ count4, float* __restrict__ C) {
  const int lane = threadIdx.x & 63;
  const int m    = blockIdx.x * 4 + (threadIdx.x >> 6);
  const char* wtb = (const char*)WT;
  const unsigned* rl = glist + (size_t)m * RCAP;

  float a0 = 0.f, a1 = 0.f, a2 = 0.f, a3 = 0.f,
        a4 = 0.f, a5 = 0.f, a6 = 0.f, a7 = 0.f;

#define FMA8(f, q)                                                          \
  {                                                                         \
    a0 = fmaf(f, __uint_as_float((q).x << 16), a0);                         \
    a1 = fmaf(f, __uint_as_float((q).x & 0xffff0000u), a1);                 \
    a2 = fmaf(f, __uint_as_float((q).y << 16), a2);                         \
    a3 = fmaf(f, __uint_as_float((q).y & 0xffff0000u), a3);                 \
    a4 = fmaf(f, __uint_as_float((q).z << 16), a4);                         \
    a5 = fmaf(f, __uint_as_float((q).z & 0xffff0000u), a5);                 \
    a6 = fmaf(f, __uint_as_float((q).w << 16), a6);                         \
    a7 = fmaf(f, __uint_as_float((q).w & 0xffff0000u), a7);                 \
  }

  u32x4 cq = count4[m];
  if (cq.x == 0xFFFFFFFFu) {
    // exact fallback: fused re-scan (never taken at ~1% density)
    const float* arow = A + (size_t)m * KDIM;
    for (int it = 0; it < KDIM / 256; ++it) {
      f32x4 av = *(const f32x4*)(arow + it * 256 + lane * 4);
      #pragma unroll
      for (int j = 0; j < 4; ++j) {
        unsigned long long msk = __ballot(av[j] != 0.0f);
        while (msk) {
          int s = __builtin_ctzll(msk); msk &= msk - 1;
          float f = __shfl(av[j], s, 64);
          int v = it * 256 + s * 4 + j;
          u32x4 q = *(const u32x4*)(wtb + (size_t)v * (NDIM * 2) + lane * 16);
          FMA8(f, q);
        }
      }
    }
  } else {
    unsigned bounds[5] = {0u, cq.x, cq.y, cq.z, cq.w};
    #pragma unroll
    for (int qtr = 0; qtr < 4; ++qtr) {
      const int beg = (int)bounds[qtr];
      const int end = (int)bounds[qtr + 1];
      if (beg >= end) continue;
      int i0 = beg + (lane & 7);
      unsigned pr = (i0 < end) ? rl[i0] : 0u;
      for (int g = beg; g < end; g += 8) {
        unsigned pk[8];
        #pragma unroll
        for (int k = 0; k < 8; ++k) pk[k] = __shfl(pr, k, 8);
        u32x4 qv[8];
        #pragma unroll
        for (int k = 0; k < 8; ++k) {
          // padded slots have pk==0 -> f=0, v=0: gathers row 0, adds 0
          unsigned mask = (g + k < end) ? 0xFFFFFFFFu : 0u;
          unsigned p = pk[k] & mask;
          qv[k] = *(const u32x4*)(wtb + (size_t)(p & 8191u) * (NDIM * 2) + lane * 16);
          pk[k] = p;
        }
        int gn = g + 8 + (lane & 7);
        if (g + 8 < end) pr = (gn < end) ? rl[gn] : 0u;
        #pragma unroll
        for (int k = 0; k < 8; ++k) {
          float f = __uint_as_float(pk[k] & 0xFFFF0000u);
          FMA8(f, qv[k]);
        }
      }
    }
  }

  float* crow = C + (size_t)m * NDIM + lane * 8;
  f32x4 o0 = {tanhf(a0), tanhf(a1), tanhf(a2), tanhf(a3)};
  f32x4 o1 = {tanhf(a4), tanhf(a5), tanhf(a6), tanhf(a7)};
  *(f32x4*)(crow + 0) = o0;
  *(f32x4*)(crow + 4) = o1;
#undef FMA8
}

// ---------------------------------------------------------------------------
extern "C" void kernel_launch(void* const* d_in, const int* in_sizes, int n_in,
                              void* d_out, int out_size, void* d_ws, size_t ws_size,
                              hipStream_t stream) {
  const float* x = (const float*)d_in[0];  // [8192, 8192] f32
  const float* W = (const float*)d_in[1];  // [512, 8192]  f32
  float* out = (float*)d_out;              // [8192, 512]  f32
  char* ws = (char*)d_ws;
  __bf16*   WT = (__bf16*)ws;
  unsigned* gl = (unsigned*)(ws + WS_GLIST);
  u32x4*    c4 = (u32x4*)(ws + WS_COUNT);

  transpose_w <<<dim3(1024),       dim3(256), 0, stream>>>(W, WT);
  scan_compact<<<dim3(M_ROWS / 4), dim3(256), 0, stream>>>(x, gl, c4);
  gather_tanh <<<dim3(M_ROWS / 4), dim3(256), 0, stream>>>(x, WT, gl, c4, out);
}